// Round 6
// baseline (498.759 us; speedup 1.0000x reference)
//
#include <hip/hip_runtime.h>
#include <math.h>

// MemoryGraphBackprop forward: 64-step recurrence over sparse neuron graph.
// BS=2, T=64, C=64, D=64, N=1024, K=32.
// received[b,n,:] = sum_k w[n,k] * pm_prev[b, idx[n,k], :]
// h = d_t*h + (1-d_t)*(received + l2norm(cc_t) on first C neurons)
// pm = tanh(h*prim);  out[b,t] = pm[:, :C]
//
// R6 = R5 (point-to-point dataflow + L2-cacheable gathers) with the tag-init
// prologue RESTORED (R5 relied on 0xAA poison for "not ready"; the harness
// only guarantees poisoning before timed launches, so the first correctness
// call could see done[]==0 == "ready" and race).
//
// Coherence argument for PLAIN gather loads (W == TT == full history):
//  - each ring address is written exactly ONCE per launch (slot t, neuron n),
//  - the producer drains vmcnt(0) BEFORE publishing done[t][n] (sc -> IC),
//  - a consumer first-touches slot-t data only AFTER seeing the tag (sc load),
//  - kernel-launch acquire invalidates L1/L2, so no pre-launch stale lines.
//  => a plain load can never observe a stale copy; ~32-way per-row read reuse
//     now lands in per-XCD L2/L1 instead of hammering the Infinity Cache.
// Fallback (ws too small for W=64): sc gathers + watermark WAR gate (R4 path).

#define NN   1024
#define TT   64
#define CCn  64
#define DD   64
#define KC   32
#define TPB  256
#define WORKBLK 256              // worker blocks (4 waves each = 1024 waves)
#define NBLK (WORKBLK + 1)       // +1 aggregator block (idle when W==TT)

__device__ __forceinline__ float ld_dc(const float* p) {
    return __hip_atomic_load(p, __ATOMIC_RELAXED, __HIP_MEMORY_SCOPE_AGENT);
}
__device__ __forceinline__ void st_dc(float* p, float v) {
    __hip_atomic_store(p, v, __ATOMIC_RELAXED, __HIP_MEMORY_SCOPE_AGENT);
}
__device__ __forceinline__ int ld_dci(const int* p) {
    return __hip_atomic_load(p, __ATOMIC_RELAXED, __HIP_MEMORY_SCOPE_AGENT);
}
__device__ __forceinline__ void st_dci(int* p, int v) {
    __hip_atomic_store(p, v, __ATOMIC_RELAXED, __HIP_MEMORY_SCOPE_AGENT);
}

__global__ void mg_init(int* ints, int total) {
    const int i = (int)blockIdx.x * (int)blockDim.x + (int)threadIdx.x;
    if (i < total) st_dci(ints + i, -1);
}

__global__ __launch_bounds__(TPB) void mg_step(
    const float* __restrict__ cc,     // [BS,T,C,D]
    const int*   __restrict__ eot,    // [BS,T]
    const int*   __restrict__ cidx,   // [N,K]
    const float* __restrict__ cw,     // [N,K]
    const float* __restrict__ prim,   // [N,D]
    const float* __restrict__ dlog,   // [N]
    const float* __restrict__ h0,     // [BS,N,D]
    const float* __restrict__ pm0,    // [BS,N,D]
    float*       __restrict__ out,    // [BS,T,C,D]
    float*       __restrict__ pmring, // [W][BS][N][D]
    int*         __restrict__ done,   // [W][N]   (-1 == not ready)
    int*         __restrict__ epoch,  // [N]
    int*         __restrict__ wm,     // [1]
    int W, int use_plain)
{
    // ---------------- aggregator block: watermark = min(epoch) -------------
    if (blockIdx.x == WORKBLK) {
        if (W >= TT) return;                       // full history: no WAR gating
        if (threadIdx.x >= 64) return;
        const int lane = threadIdx.x;
        int cur = -1;
        while (cur < TT - 1) {
            int m = 0x7fffffff;
            #pragma unroll
            for (int c = 0; c < NN; c += 64)
                m = min(m, ld_dci(epoch + c + lane));
            #pragma unroll
            for (int off = 32; off >= 1; off >>= 1)
                m = min(m, __shfl_xor(m, off, 64));
            if (m > cur) { cur = m; if (lane == 0) st_dci(wm, cur); }
            else __builtin_amdgcn_s_sleep(4);
        }
        return;
    }

    // ---------------- worker: wave <-> neuron ------------------------------
    const int lane = threadIdx.x & 63;
    const int wv   = __builtin_amdgcn_readfirstlane((int)threadIdx.x >> 6);
    const int n    = (int)blockIdx.x * 4 + wv;               // 0..1023, uniform

    int   ipr[KC];
    float wr[KC];
    #pragma unroll
    for (int k = 0; k < KC; ++k) { ipr[k] = cidx[n * KC + k]; wr[k] = cw[n * KC + k]; }
    const int src_l = ipr[lane & 31];                        // per-lane source neuron

    const float pv  = prim[n * DD + lane];
    const float dec = 1.0f / (1.0f + expf(-dlog[n]));
    float hv0 = h0[(0 * NN + n) * DD + lane];
    float hv1 = h0[(1 * NN + n) * DD + lane];

    int wm_c = -1;
    int sr = W - 1, sw = 0;   // read slot = (t-1)%W, write slot = t%W

    for (int t = 0; t < TT; ++t) {
        // ---- wait for MY sources (t>0), then gather ----
        const float* src;
        if (t == 0) {
            src = pm0;
        } else {
            const int need = t - 1;
            const int* dn = done + sr * NN;
            while (__ballot(ld_dci(dn + src_l) >= need) != ~0ull)
                __builtin_amdgcn_s_sleep(1);
            asm volatile("" ::: "memory");   // no load may hoist above the spin
            src = pmring + (size_t)sr * (2 * NN * DD);
        }

        float g0[KC], g1[KC];
        const float* s0 = src + lane;             // batch 0
        const float* s1 = src + NN * DD + lane;   // batch 1
        if (use_plain | (t == 0)) {
            // L1/L2-cacheable gathers (safe: slot written once, read post-tag)
            #pragma unroll
            for (int k = 0; k < KC; ++k) {
                const int o = ipr[k] * DD;
                g0[k] = s0[o];
                g1[k] = s1[o];
            }
        } else {
            #pragma unroll
            for (int k = 0; k < KC; ++k) {
                const int o = ipr[k] * DD;
                g0[k] = ld_dc(s0 + o);
                g1[k] = ld_dc(s1 + o);
            }
        }

        float a0 = 0.f, a1 = 0.f, a2 = 0.f, a3 = 0.f;
        float b0 = 0.f, b1 = 0.f, b2 = 0.f, b3 = 0.f;
        #pragma unroll
        for (int k = 0; k < KC; k += 4) {
            a0 = fmaf(wr[k + 0], g0[k + 0], a0);  b0 = fmaf(wr[k + 0], g1[k + 0], b0);
            a1 = fmaf(wr[k + 1], g0[k + 1], a1);  b1 = fmaf(wr[k + 1], g1[k + 1], b1);
            a2 = fmaf(wr[k + 2], g0[k + 2], a2);  b2 = fmaf(wr[k + 2], g1[k + 2], b2);
            a3 = fmaf(wr[k + 3], g0[k + 3], a3);  b3 = fmaf(wr[k + 3], g1[k + 3], b3);
        }
        float r0 = (a0 + a1) + (a2 + a3);
        float r1 = (b0 + b1) + (b2 + b3);

        if (n < CCn) {   // cc injection with on-the-fly L2 norm, both batches
            const float v0 = cc[((0 * TT + t) * CCn + n) * DD + lane];
            const float v1 = cc[((1 * TT + t) * CCn + n) * DD + lane];
            float s0s = v0 * v0, s1s = v1 * v1;
            #pragma unroll
            for (int off = 32; off >= 1; off >>= 1) {
                s0s += __shfl_xor(s0s, off, 64);
                s1s += __shfl_xor(s1s, off, 64);
            }
            r0 += v0 * (1.0f / fmaxf(sqrtf(s0s), 1e-8f));
            r1 += v1 * (1.0f / fmaxf(sqrtf(s1s), 1e-8f));
        }

        const float e0 = (float)eot[0 * TT + t];
        const float e1 = (float)eot[1 * TT + t];
        const float dt0 = dec * (1.0f - e0);
        const float dt1 = dec * (1.0f - e1);
        hv0 = dt0 * hv0 + (1.0f - dt0) * r0;
        hv1 = dt1 * hv1 + (1.0f - dt1) * r1;
        const float p0 = tanhf(hv0 * pv);
        const float p1 = tanhf(hv1 * pv);

        // ---- WAR gate (ring wrap only; W==TT -> never) ----
        if (t >= W) {
            const int need = t - W + 1;
            if (wm_c < need) {
                while ((wm_c = ld_dci(wm)) < need) __builtin_amdgcn_s_sleep(1);
            }
            asm volatile("" ::: "memory");
        }

        // ---- publish: ring data (sc), drain ONLY these, tag, then out ----
        float* dsb = pmring + (size_t)sw * (2 * NN * DD);
        st_dc(dsb + n * DD + lane, p0);
        st_dc(dsb + NN * DD + n * DD + lane, p1);
        asm volatile("s_waitcnt vmcnt(0)" ::: "memory");
        if (lane == 0) {
            st_dci(done + sw * NN + n, t);
            if (W < TT) st_dci(epoch + n, t);
        }
        if (n < CCn) {
            out[((0 * TT + t) * CCn + n) * DD + lane] = p0;
            out[((1 * TT + t) * CCn + n) * DD + lane] = p1;
        }

        sr = (sr + 1 == W) ? 0 : sr + 1;
        sw = (sw + 1 == W) ? 0 : sw + 1;
    }
}

extern "C" void kernel_launch(void* const* d_in, const int* in_sizes, int n_in,
                              void* d_out, int out_size, void* d_ws, size_t ws_size,
                              hipStream_t stream) {
    const float* cc   = (const float*)d_in[0];
    const int*   eot  = (const int*)  d_in[1];
    const int*   cidx = (const int*)  d_in[2];
    /* d_in[3] conn_mask: all ones -> unused */
    const float* prim = (const float*)d_in[4];
    const float* cw   = (const float*)d_in[5];
    const float* dlog = (const float*)d_in[6];
    const float* h0   = (const float*)d_in[7];
    const float* pm0  = (const float*)d_in[8];
    /* d_in[9] grad_window: forward no-op */

    // ring depth W: pm ring W*BS*N*D floats + done W*N + epoch N + wm 1 (ints)
    int W = TT;                  // full history preferred (enables plain loads)
    while (W > 2) {
        size_t need = (size_t)W * 2 * NN * DD * 4 + ((size_t)W * NN + NN + 1) * 4;
        if (need <= ws_size) break;
        --W;
    }
    const int use_plain = (W >= TT) ? 1 : 0;

    float* pmring = (float*)d_ws;
    int*   ints   = (int*)(pmring + (size_t)W * 2 * NN * DD);
    int*   done   = ints;                  // [W][N]
    int*   epoch  = ints + (size_t)W * NN; // [N]
    int*   wmp    = epoch + NN;            // [1]
    const int total_ints = W * NN + NN + 1;

    hipLaunchKernelGGL(mg_init, dim3((total_ints + 255) / 256), dim3(256), 0, stream,
                       ints, total_ints);
    hipLaunchKernelGGL(mg_step, dim3(NBLK), dim3(TPB), 0, stream,
                       cc, eot, cidx, cw, prim, dlog, h0, pm0, (float*)d_out,
                       pmring, done, epoch, wmp, W, use_plain);
}

// Round 7
// 339.659 us; speedup vs baseline: 1.4684x; 1.4684x over previous
//
#include <hip/hip_runtime.h>
#include <math.h>

// MemoryGraphBackprop forward: 64-step recurrence over sparse neuron graph.
// BS=2, T=64, C=64, D=64, N=1024, K=32.
// received[b,n,:] = sum_k w[n,k] * pm_prev[b, idx[n,k], :]
// h = d_t*h + (1-d_t)*(received + l2norm(cc_t) on first C neurons)
// pm = tanh(h*prim);  out[b,t] = pm[:, :C]
//
// R7: push-notification dataflow. R4/R6 A/B showed gather path is NOT the
// bottleneck (sc vs L2-cached gathers: 437 vs 440 us). Theory: the cost is
// poll contention -- 1024 waves x 32 scattered sc tag-reads into ONE 4KB
// region = ~1M 4B coherent requests/step into a few IC slices. Fix:
//  - prologue builds reverse adjacency (CSR) in d_ws,
//  - producer: pm sc stores -> vmcnt(0) -> one relaxed agent atomicAdd per
//    out-edge into consumer inboxes (64B-padded, 64KB region, slice-spread),
//  - consumer: spins on ONE address (own inbox) until inbox >= 32*t
//    (duplicate edges self-consistently count: in-degree == 32 exactly).
// Gathers stay PLAIN (write-once full-history ring => never stale).
// Fallback (ws too small): R3-style epoch barrier + sc gathers.

#define NN   1024
#define TT   64
#define CCn  64
#define DD   64
#define KC   32
#define TPB  256
#define NBLK 256                 // 4 waves/block -> 1024 waves = 1024 neurons
#define NEDGE (NN * KC)          // 32768
#define IBSTRIDE 16              // inbox padding: 16 ints = 64B line

__device__ __forceinline__ float ld_dc(const float* p) {
    return __hip_atomic_load(p, __ATOMIC_RELAXED, __HIP_MEMORY_SCOPE_AGENT);
}
__device__ __forceinline__ void st_dc(float* p, float v) {
    __hip_atomic_store(p, v, __ATOMIC_RELAXED, __HIP_MEMORY_SCOPE_AGENT);
}
__device__ __forceinline__ int ld_dci(const int* p) {
    return __hip_atomic_load(p, __ATOMIC_RELAXED, __HIP_MEMORY_SCOPE_AGENT);
}
__device__ __forceinline__ void st_dci(int* p, int v) {
    __hip_atomic_store(p, v, __ATOMIC_RELAXED, __HIP_MEMORY_SCOPE_AGENT);
}

__device__ __forceinline__ float fast_tanh(float x) {
    x = fminf(9.0f, fmaxf(-9.0f, x));
    const float e = __expf(2.0f * x);
    return (e - 1.0f) / (e + 1.0f);
}

// ---- prologue: zero the int region ----
__global__ void mg_zero(int* p, int total) {
    const int i = (int)blockIdx.x * (int)blockDim.x + (int)threadIdx.x;
    if (i < total) p[i] = 0;
}
// ---- prologue: out-degree histogram ----
__global__ void mg_count(const int* __restrict__ cidx, int* __restrict__ cnt) {
    const int e = (int)blockIdx.x * (int)blockDim.x + (int)threadIdx.x;
    if (e < NEDGE) atomicAdd(cnt + cidx[e], 1);
}
// ---- prologue: exclusive offsets via single-block scan; reset cnt ----
__global__ __launch_bounds__(1024) void mg_scan(const int* __restrict__ cnt_in,
                                                int* __restrict__ ofs,
                                                int* __restrict__ cnt_reset) {
    __shared__ int sh[1024];
    const int t = threadIdx.x;
    sh[t] = cnt_in[t];
    __syncthreads();
    for (int off = 1; off < 1024; off <<= 1) {
        int v = (t >= off) ? sh[t - off] : 0;
        __syncthreads();
        sh[t] += v;
        __syncthreads();
    }
    ofs[t + 1] = sh[t];
    if (t == 0) ofs[0] = 0;
    cnt_reset[t] = 0;
}
// ---- prologue: fill edge lists (consumer ids per source neuron) ----
__global__ void mg_fill(const int* __restrict__ cidx, const int* __restrict__ ofs,
                        int* __restrict__ cur, int* __restrict__ edges) {
    const int e = (int)blockIdx.x * (int)blockDim.x + (int)threadIdx.x;
    if (e < NEDGE) {
        const int s = cidx[e];          // source neuron
        const int j = e >> 5;           // consumer neuron (row of cidx)
        const int pos = atomicAdd(cur + s, 1);
        edges[ofs[s] + pos] = j;
    }
}

__global__ __launch_bounds__(TPB) void mg_step(
    const float* __restrict__ cc,     // [BS,T,C,D]
    const int*   __restrict__ eot,    // [BS,T]
    const int*   __restrict__ cidx,   // [N,K]
    const float* __restrict__ cw,     // [N,K]
    const float* __restrict__ prim,   // [N,D]
    const float* __restrict__ dlog,   // [N]
    const float* __restrict__ h0,     // [BS,N,D]
    const float* __restrict__ pm0,    // [BS,N,D]
    float*       __restrict__ out,    // [BS,T,C,D]
    float*       __restrict__ pmring, // [W][BS][N][D]
    int*         __restrict__ inbox,  // [N*IBSTRIDE]
    const int*   __restrict__ ofs,    // [N+1]
    const int*   __restrict__ edges,  // [NEDGE]
    int*         __restrict__ flags,  // [NBLK] (fallback barrier)
    int W, int fastmode)
{
    const int lane = threadIdx.x & 63;
    const int wv   = __builtin_amdgcn_readfirstlane((int)threadIdx.x >> 6);
    const int n    = (int)blockIdx.x * 4 + wv;               // 0..1023, uniform

    int   ipr[KC];
    float wr[KC];
    #pragma unroll
    for (int k = 0; k < KC; ++k) { ipr[k] = cidx[n * KC + k]; wr[k] = cw[n * KC + k]; }

    const float pv  = prim[n * DD + lane];
    const float dec = 1.0f / (1.0f + __expf(-dlog[n]));
    float hv0 = h0[(0 * NN + n) * DD + lane];
    float hv1 = h0[(1 * NN + n) * DD + lane];

    // eot packed into two 64-bit masks (bit t)
    const unsigned long long m0 = __ballot(eot[0 * TT + lane] != 0);
    const unsigned long long m1 = __ballot(eot[1 * TT + lane] != 0);

    const int ofsn = ofs[n];
    const int deg  = ofs[n + 1] - ofsn;
    int* ib = inbox + n * IBSTRIDE;

    for (int t = 0; t < TT; ++t) {
        const int sr = fastmode ? (t - 1) : ((t - 1) % W + ((t - 1) % W < 0 ? W : 0));
        const int sw = fastmode ? t : (t % W);

        // ---- wait for sources ----
        const float* src;
        if (t == 0) {
            src = pm0;
        } else {
            if (fastmode) {
                const int need = KC * t;             // exactly K notifies per step
                while (ld_dci(ib) < need) __builtin_amdgcn_s_sleep(1);
            } else {
                // fallback: contention-free epoch barrier (R3 style)
                // (arrival was published at end of previous iteration)
                const int tgt = t;
                const int* fp = flags + lane;
                bool ok;
                do {
                    ok = (ld_dci(fp) >= tgt) & (ld_dci(fp + 64) >= tgt) &
                         (ld_dci(fp + 128) >= tgt) & (ld_dci(fp + 192) >= tgt);
                    if (__ballot(ok) == ~0ull) break;
                    __builtin_amdgcn_s_sleep(1);
                } while (true);
                __syncthreads();
            }
            asm volatile("" ::: "memory");   // no load may hoist above the spin
            src = pmring + (size_t)sr * (2 * NN * DD);
        }

        // ---- gather ----
        float g0[KC], g1[KC];
        const float* s0 = src + lane;             // batch 0
        const float* s1 = src + NN * DD + lane;   // batch 1
        if (fastmode | (t == 0)) {
            #pragma unroll
            for (int k = 0; k < KC; ++k) {        // plain: write-once ring, L1/L2 OK
                const int o = ipr[k] * DD;
                g0[k] = s0[o];
                g1[k] = s1[o];
            }
        } else {
            #pragma unroll
            for (int k = 0; k < KC; ++k) {
                const int o = ipr[k] * DD;
                g0[k] = ld_dc(s0 + o);
                g1[k] = ld_dc(s1 + o);
            }
        }

        float a0 = 0.f, a1 = 0.f, a2 = 0.f, a3 = 0.f;
        float b0 = 0.f, b1 = 0.f, b2 = 0.f, b3 = 0.f;
        #pragma unroll
        for (int k = 0; k < KC; k += 4) {
            a0 = fmaf(wr[k + 0], g0[k + 0], a0);  b0 = fmaf(wr[k + 0], g1[k + 0], b0);
            a1 = fmaf(wr[k + 1], g0[k + 1], a1);  b1 = fmaf(wr[k + 1], g1[k + 1], b1);
            a2 = fmaf(wr[k + 2], g0[k + 2], a2);  b2 = fmaf(wr[k + 2], g1[k + 2], b2);
            a3 = fmaf(wr[k + 3], g0[k + 3], a3);  b3 = fmaf(wr[k + 3], g1[k + 3], b3);
        }
        float r0 = (a0 + a1) + (a2 + a3);
        float r1 = (b0 + b1) + (b2 + b3);

        if (n < CCn) {   // cc injection with on-the-fly L2 norm, both batches
            const float v0 = cc[((0 * TT + t) * CCn + n) * DD + lane];
            const float v1 = cc[((1 * TT + t) * CCn + n) * DD + lane];
            float s0s = v0 * v0, s1s = v1 * v1;
            #pragma unroll
            for (int off = 32; off >= 1; off >>= 1) {
                s0s += __shfl_xor(s0s, off, 64);
                s1s += __shfl_xor(s1s, off, 64);
            }
            r0 += v0 * (1.0f / fmaxf(sqrtf(s0s), 1e-8f));
            r1 += v1 * (1.0f / fmaxf(sqrtf(s1s), 1e-8f));
        }

        const float e0 = (float)((m0 >> t) & 1ull);
        const float e1 = (float)((m1 >> t) & 1ull);
        const float dt0 = dec * (1.0f - e0);
        const float dt1 = dec * (1.0f - e1);
        hv0 = dt0 * hv0 + (1.0f - dt0) * r0;
        hv1 = dt1 * hv1 + (1.0f - dt1) * r1;
        const float p0 = fast_tanh(hv0 * pv);
        const float p1 = fast_tanh(hv1 * pv);

        // ---- publish: ring data (sc), drain, then notify consumers ----
        float* dsb = pmring + (size_t)sw * (2 * NN * DD);
        st_dc(dsb + n * DD + lane, p0);
        st_dc(dsb + NN * DD + n * DD + lane, p1);
        asm volatile("s_waitcnt vmcnt(0)" ::: "memory");

        if (fastmode) {
            if (t < TT - 1) {
                for (int l = lane; l < deg; l += 64) {
                    const int j = edges[ofsn + l];
                    __hip_atomic_fetch_add(inbox + j * IBSTRIDE, 1,
                                           __ATOMIC_RELAXED, __HIP_MEMORY_SCOPE_AGENT);
                }
            }
        } else {
            __syncthreads();                       // all 4 waves drained
            if (threadIdx.x == 0) st_dci(flags + blockIdx.x, t + 1);
        }

        if (n < CCn) {                             // out after notify (off critical path)
            out[((0 * TT + t) * CCn + n) * DD + lane] = p0;
            out[((1 * TT + t) * CCn + n) * DD + lane] = p1;
        }
    }
}

extern "C" void kernel_launch(void* const* d_in, const int* in_sizes, int n_in,
                              void* d_out, int out_size, void* d_ws, size_t ws_size,
                              hipStream_t stream) {
    const float* cc   = (const float*)d_in[0];
    const int*   eot  = (const int*)  d_in[1];
    const int*   cidx = (const int*)  d_in[2];
    /* d_in[3] conn_mask: all ones -> unused */
    const float* prim = (const float*)d_in[4];
    const float* cw   = (const float*)d_in[5];
    const float* dlog = (const float*)d_in[6];
    const float* h0   = (const float*)d_in[7];
    const float* pm0  = (const float*)d_in[8];
    /* d_in[9] grad_window: forward no-op */

    // int region: inbox[N*16] | ofs[N+1] | cnt[N] | edges[NEDGE] | flags[NBLK]
    const size_t n_ints = (size_t)NN * IBSTRIDE + (NN + 1) + NN + NEDGE + NBLK;

    int W = TT;                  // full history preferred (enables fast mode)
    while (W > 2) {
        size_t need = (size_t)W * 2 * NN * DD * 4 + n_ints * 4;
        if (need <= ws_size) break;
        --W;
    }
    const int fastmode = (W >= TT) ? 1 : 0;

    float* pmring = (float*)d_ws;
    int*   ints   = (int*)(pmring + (size_t)W * 2 * NN * DD);
    int*   inbox  = ints;
    int*   ofs    = inbox + (size_t)NN * IBSTRIDE;
    int*   cnt    = ofs + (NN + 1);
    int*   edges  = cnt + NN;
    int*   flags  = edges + NEDGE;

    hipLaunchKernelGGL(mg_zero, dim3(((int)n_ints + 255) / 256), dim3(256), 0, stream,
                       ints, (int)n_ints);
    hipLaunchKernelGGL(mg_count, dim3(NEDGE / 256), dim3(256), 0, stream, cidx, cnt);
    hipLaunchKernelGGL(mg_scan, dim3(1), dim3(1024), 0, stream, cnt, ofs, cnt);
    hipLaunchKernelGGL(mg_fill, dim3(NEDGE / 256), dim3(256), 0, stream,
                       cidx, ofs, cnt, edges);
    hipLaunchKernelGGL(mg_step, dim3(NBLK), dim3(TPB), 0, stream,
                       cc, eot, cidx, cw, prim, dlog, h0, pm0, (float*)d_out,
                       pmring, inbox, ofs, edges, flags, W, fastmode);
}

// Round 8
// 273.614 us; speedup vs baseline: 1.8229x; 1.2414x over previous
//
#include <hip/hip_runtime.h>
#include <math.h>

// MemoryGraphBackprop forward: 64-step recurrence over sparse neuron graph.
// BS=2, T=64, C=64, D=64, N=1024, K=32.
// received[b,n,:] = sum_k w[n,k] * pm_prev[b, idx[n,k], :]
// h = d_t*h + (1-d_t)*(received + l2norm(cc_t) on first C neurons)
// pm = tanh(h*prim);  out[b,t] = pm[:, :C]
//
// R8: self-tagging data (no tags, no atomics, no drains).
// Ladder so far: grid barrier 15us/step -> epoch barrier 10 -> p2p tags 6.8
// -> push-notify 4. Remaining cost = ~4 coherent RTs in the per-step chain
// (drain -> notify -> notice -> gather). Fix: full-history ring is write-once,
// so encode validity IN the value: producer stores pm+4 (valid range [3,5];
// zeros/0xAA poison < 2 = invalid). Consumer polls its 64 gather values
// directly (sc loads, bypass L1/L2 so re-polls see fresh IC data) until all
// >= 2, then uses them in-place: recv = dot(w,g) - 4*sum(w). Chain collapses
// to: producer sc-store -> IC, consumer's next poll reads it (~1.5 RTs).
// Ring explicitly zeroed each launch (hipMemsetAsync) - validity encoding
// must not depend on harness poison. Fallback (small ws): epoch barrier,
// unbiased stores, sc gathers.

#define NN   1024
#define TT   64
#define CCn  64
#define DD   64
#define KC   32
#define TPB  256
#define NBLK 256                 // 4 waves/block -> 1024 waves = 1024 neurons
#define BIAS 4.0f
#define VTHR 2.0f

__device__ __forceinline__ float ld_dc(const float* p) {
    return __hip_atomic_load(p, __ATOMIC_RELAXED, __HIP_MEMORY_SCOPE_AGENT);
}
__device__ __forceinline__ void st_dc(float* p, float v) {
    __hip_atomic_store(p, v, __ATOMIC_RELAXED, __HIP_MEMORY_SCOPE_AGENT);
}
__device__ __forceinline__ int ld_dci(const int* p) {
    return __hip_atomic_load(p, __ATOMIC_RELAXED, __HIP_MEMORY_SCOPE_AGENT);
}
__device__ __forceinline__ void st_dci(int* p, int v) {
    __hip_atomic_store(p, v, __ATOMIC_RELAXED, __HIP_MEMORY_SCOPE_AGENT);
}

__device__ __forceinline__ float fast_tanh(float x) {
    x = fminf(9.0f, fmaxf(-9.0f, x));
    const float e = __expf(2.0f * x);
    return (e - 1.0f) / (e + 1.0f);
}

__global__ __launch_bounds__(TPB) void mg_step(
    const float* __restrict__ cc,     // [BS,T,C,D]
    const int*   __restrict__ eot,    // [BS,T]
    const int*   __restrict__ cidx,   // [N,K]
    const float* __restrict__ cw,     // [N,K]  (conn_mask all-ones; skipped)
    const float* __restrict__ prim,   // [N,D]
    const float* __restrict__ dlog,   // [N]
    const float* __restrict__ h0,     // [BS,N,D]
    const float* __restrict__ pm0,    // [BS,N,D]
    float*       __restrict__ out,    // [BS,T,C,D]
    float*       __restrict__ pmring, // [W][BS][N][D], zeroed at launch
    int*         __restrict__ flags,  // [NBLK] (fallback barrier, zeroed)
    int W, int fastmode)
{
    const int lane = threadIdx.x & 63;
    const int wv   = __builtin_amdgcn_readfirstlane((int)threadIdx.x >> 6);
    const int n    = (int)blockIdx.x * 4 + wv;               // 0..1023, uniform

    int   ipr[KC];
    float wr[KC];
    float swsum = 0.0f;
    #pragma unroll
    for (int k = 0; k < KC; ++k) {
        ipr[k] = cidx[n * KC + k];
        wr[k]  = cw[n * KC + k];
        swsum += wr[k];
    }

    const float pv  = prim[n * DD + lane];
    const float dec = 1.0f / (1.0f + __expf(-dlog[n]));
    float hv0 = h0[(0 * NN + n) * DD + lane];
    float hv1 = h0[(1 * NN + n) * DD + lane];

    // eot packed into two 64-bit masks (bit t)
    const unsigned long long m0 = __ballot(eot[0 * TT + lane] != 0);
    const unsigned long long m1 = __ballot(eot[1 * TT + lane] != 0);

    for (int t = 0; t < TT; ++t) {
        float g0[KC], g1[KC];
        float bias_corr = 0.0f;

        if (t == 0) {
            const float* s0 = pm0 + lane;
            const float* s1 = pm0 + NN * DD + lane;
            #pragma unroll
            for (int k = 0; k < KC; ++k) {
                const int o = ipr[k] * DD;
                g0[k] = s0[o];
                g1[k] = s1[o];
            }
        } else if (fastmode) {
            // ---- self-tagging poll: re-read gather set until all valid ----
            const float* s0 = pmring + (size_t)(t - 1) * (2 * NN * DD) + lane;
            const float* s1 = s0 + NN * DD;
            for (;;) {
                #pragma unroll
                for (int k = 0; k < KC; ++k) {
                    const int o = ipr[k] * DD;
                    g0[k] = ld_dc(s0 + o);
                    g1[k] = ld_dc(s1 + o);
                }
                float mn = g0[0];
                #pragma unroll
                for (int k = 0; k < KC; ++k) mn = fminf(mn, fminf(g0[k], g1[k]));
                if (__ballot(mn >= VTHR) == ~0ull) break;   // all 64 lanes valid
            }
            asm volatile("" ::: "memory");
            bias_corr = BIAS * swsum;
        } else {
            // ---- fallback: epoch barrier (publish happened end of prev step) ----
            const int* fp = flags + lane;
            for (;;) {
                const bool ok = (ld_dci(fp) >= t) & (ld_dci(fp + 64) >= t) &
                                (ld_dci(fp + 128) >= t) & (ld_dci(fp + 192) >= t);
                if (__ballot(ok) == ~0ull) break;
                __builtin_amdgcn_s_sleep(1);
            }
            __syncthreads();
            asm volatile("" ::: "memory");
            const float* s0 = pmring + (size_t)((t - 1) % W) * (2 * NN * DD) + lane;
            const float* s1 = s0 + NN * DD;
            #pragma unroll
            for (int k = 0; k < KC; ++k) {
                const int o = ipr[k] * DD;
                g0[k] = ld_dc(s0 + o);
                g1[k] = ld_dc(s1 + o);
            }
        }

        float a0 = 0.f, a1 = 0.f, a2 = 0.f, a3 = 0.f;
        float b0 = 0.f, b1 = 0.f, b2 = 0.f, b3 = 0.f;
        #pragma unroll
        for (int k = 0; k < KC; k += 4) {
            a0 = fmaf(wr[k + 0], g0[k + 0], a0);  b0 = fmaf(wr[k + 0], g1[k + 0], b0);
            a1 = fmaf(wr[k + 1], g0[k + 1], a1);  b1 = fmaf(wr[k + 1], g1[k + 1], b1);
            a2 = fmaf(wr[k + 2], g0[k + 2], a2);  b2 = fmaf(wr[k + 2], g1[k + 2], b2);
            a3 = fmaf(wr[k + 3], g0[k + 3], a3);  b3 = fmaf(wr[k + 3], g1[k + 3], b3);
        }
        float r0 = (a0 + a1) + (a2 + a3) - bias_corr;
        float r1 = (b0 + b1) + (b2 + b3) - bias_corr;

        if (n < CCn) {   // cc injection with on-the-fly L2 norm, both batches
            const float v0 = cc[((0 * TT + t) * CCn + n) * DD + lane];
            const float v1 = cc[((1 * TT + t) * CCn + n) * DD + lane];
            float s0s = v0 * v0, s1s = v1 * v1;
            #pragma unroll
            for (int off = 32; off >= 1; off >>= 1) {
                s0s += __shfl_xor(s0s, off, 64);
                s1s += __shfl_xor(s1s, off, 64);
            }
            r0 += v0 * (1.0f / fmaxf(sqrtf(s0s), 1e-8f));
            r1 += v1 * (1.0f / fmaxf(sqrtf(s1s), 1e-8f));
        }

        const float e0 = (float)((m0 >> t) & 1ull);
        const float e1 = (float)((m1 >> t) & 1ull);
        const float dt0 = dec * (1.0f - e0);
        const float dt1 = dec * (1.0f - e1);
        hv0 = dt0 * hv0 + (1.0f - dt0) * r0;
        hv1 = dt1 * hv1 + (1.0f - dt1) * r1;
        const float p0 = fast_tanh(hv0 * pv);
        const float p1 = fast_tanh(hv1 * pv);

        if (fastmode) {
            if (t < TT - 1) {           // slot TT-1 never read
                float* dsb = pmring + (size_t)t * (2 * NN * DD);
                st_dc(dsb + n * DD + lane, p0 + BIAS);        // data IS the tag
                st_dc(dsb + NN * DD + n * DD + lane, p1 + BIAS);
            }
        } else {
            float* dsb = pmring + (size_t)(t % W) * (2 * NN * DD);
            st_dc(dsb + n * DD + lane, p0);
            st_dc(dsb + NN * DD + n * DD + lane, p1);
            asm volatile("s_waitcnt vmcnt(0)" ::: "memory");
            __syncthreads();
            if (threadIdx.x == 0) st_dci(flags + blockIdx.x, t + 1);
        }

        if (n < CCn) {                  // off the critical path
            out[((0 * TT + t) * CCn + n) * DD + lane] = p0;
            out[((1 * TT + t) * CCn + n) * DD + lane] = p1;
        }
    }
}

extern "C" void kernel_launch(void* const* d_in, const int* in_sizes, int n_in,
                              void* d_out, int out_size, void* d_ws, size_t ws_size,
                              hipStream_t stream) {
    const float* cc   = (const float*)d_in[0];
    const int*   eot  = (const int*)  d_in[1];
    const int*   cidx = (const int*)  d_in[2];
    /* d_in[3] conn_mask: all ones -> unused */
    const float* prim = (const float*)d_in[4];
    const float* cw   = (const float*)d_in[5];
    const float* dlog = (const float*)d_in[6];
    const float* h0   = (const float*)d_in[7];
    const float* pm0  = (const float*)d_in[8];
    /* d_in[9] grad_window: forward no-op */

    // layout: pmring [W][2][N][D] floats | flags [NBLK] ints
    int W = TT;                  // full history preferred (enables fast mode)
    while (W > 2) {
        size_t need = (size_t)W * 2 * NN * DD * 4 + (size_t)NBLK * 4;
        if (need <= ws_size) break;
        --W;
    }
    const int fastmode = (W >= TT) ? 1 : 0;

    float* pmring = (float*)d_ws;
    int*   flags  = (int*)(pmring + (size_t)W * 2 * NN * DD);
    const size_t clear_bytes = (size_t)W * 2 * NN * DD * 4 + (size_t)NBLK * 4;

    // zero ring+flags: validity encoding must not trust harness poison
    hipMemsetAsync(d_ws, 0, clear_bytes, stream);
    hipLaunchKernelGGL(mg_step, dim3(NBLK), dim3(TPB), 0, stream,
                       cc, eot, cidx, cw, prim, dlog, h0, pm0, (float*)d_out,
                       pmring, flags, W, fastmode);
}